// Round 4
// baseline (618.967 us; speedup 1.0000x reference)
//
#include <hip/hip_runtime.h>
#include <math.h>

// Problem constants
#define BATCH 8
#define CDIM 512       // DIM
#define XY 1024        // X*Y = 32*32
#define NCTX 1024
#define HEADS 8
#define DHEAD 64
#define EINNER 512     // HEADS*DHEAD
#define E2 1024        // 2*EINNER

#define SQRT_DIM 22.627416997969522f  // sqrt(512)

typedef short bf16x8 __attribute__((ext_vector_type(8)));
typedef float f32x4 __attribute__((ext_vector_type(4)));
typedef unsigned short ushort4v __attribute__((ext_vector_type(4)));

// float -> bf16 bits (RNE)
__device__ __forceinline__ unsigned short f2bf(float x) {
    unsigned int u = __builtin_bit_cast(unsigned int, x);
    return (unsigned short)((u + 0x7fffu + ((u >> 16) & 1u)) >> 16);
}
__device__ __forceinline__ float bf2f(unsigned short h) {
    unsigned int u = ((unsigned int)h) << 16;
    return __builtin_bit_cast(float, u);
}

// ---------------------------------------------------------------------------
// Kernel 1: per-(b,xy) channel-RMSNorm scale for fmap  [b][c][xy]
// ---------------------------------------------------------------------------
__global__ __launch_bounds__(256) void k_fmap_scale(const float* __restrict__ fmap,
                                                    float* __restrict__ fscale) {
    int t = blockIdx.x * 256 + threadIdx.x;       // 0..8191 = B*XY
    int b = t >> 10;
    const float* p = fmap + (size_t)b * CDIM * XY + (t & 1023);
    float ss = 0.f;
#pragma unroll 8
    for (int c = 0; c < CDIM; ++c) {
        float v = p[(size_t)c * XY];
        ss = fmaf(v, v, ss);
    }
    fscale[t] = SQRT_DIM / fmaxf(sqrtf(ss), 1e-12f);
}

// ---------------------------------------------------------------------------
// Kernel 2: per-(b,n) RMSNorm scale for context [b][n][c]
// ---------------------------------------------------------------------------
__global__ __launch_bounds__(256) void k_ctx_scale(const float* __restrict__ ctx,
                                                   float* __restrict__ cscale) {
    int row = blockIdx.x * 4 + (threadIdx.x >> 6);
    int lane = threadIdx.x & 63;
    const float* p = ctx + (size_t)row * CDIM;
    float ss = 0.f;
#pragma unroll
    for (int k = 0; k < CDIM / 64; ++k) {
        float v = p[lane + 64 * k];
        ss = fmaf(v, v, ss);
    }
#pragma unroll
    for (int off = 32; off; off >>= 1) ss += __shfl_down(ss, off, 64);
    if (lane == 0) cscale[row] = SQRT_DIM / fmaxf(sqrtf(ss), 1e-12f);
}

// ---------------------------------------------------------------------------
// GEMM NN: C[b][m][n] = sum_k A[m][k] * Bop[b][k][n]   (fp32, 64x64 tile)
// ---------------------------------------------------------------------------
template <bool SCALE_B>
__global__ __launch_bounds__(256) void k_gemm_nn(const float* __restrict__ A,
                                                 const float* __restrict__ Bm,
                                                 float* __restrict__ Cm,
                                                 const float* __restrict__ colscale,
                                                 const float* __restrict__ rowgamma,
                                                 int M, int N, int K) {
    const int b = blockIdx.z;
    const int n0 = blockIdx.x * 64, m0 = blockIdx.y * 64;
    const float* Bb = Bm + (size_t)b * K * N;
    float* Cb = Cm + (size_t)b * M * N;
    __shared__ float As[16][68];
    __shared__ float Bs[16][68];
    const int t = threadIdx.x;
    const int tr = t >> 4, tc = t & 15;
    const int la_k = t & 15, la_m = t >> 4;
    const int lb_n = t & 63, lb_k = t >> 6;
    float acc[4][4] = {};

    float cs = 1.f;
    if constexpr (SCALE_B) cs = colscale[(size_t)b * N + n0 + lb_n];

    for (int k0 = 0; k0 < K; k0 += 16) {
        __syncthreads();
#pragma unroll
        for (int i = 0; i < 4; ++i) {
            int m = la_m + 16 * i;
            As[la_k][m] = A[(size_t)(m0 + m) * K + k0 + la_k];
        }
#pragma unroll
        for (int i = 0; i < 4; ++i) {
            int kk = lb_k + 4 * i;
            float v = Bb[(size_t)(k0 + kk) * N + n0 + lb_n];
            if constexpr (SCALE_B) v *= cs * rowgamma[k0 + kk];
            Bs[kk][lb_n] = v;
        }
        __syncthreads();
#pragma unroll
        for (int kk = 0; kk < 16; ++kk) {
            const float4 a4 = *(const float4*)(&As[kk][tr * 4]);
            const float4 b4 = *(const float4*)(&Bs[kk][tc * 4]);
            const float ar[4] = {a4.x, a4.y, a4.z, a4.w};
            const float bc[4] = {b4.x, b4.y, b4.z, b4.w};
#pragma unroll
            for (int rr = 0; rr < 4; ++rr)
#pragma unroll
                for (int cc = 0; cc < 4; ++cc)
                    acc[rr][cc] = fmaf(ar[rr], bc[cc], acc[rr][cc]);
        }
    }
#pragma unroll
    for (int rr = 0; rr < 4; ++rr) {
        float4 v = {acc[rr][0], acc[rr][1], acc[rr][2], acc[rr][3]};
        *(float4*)(&Cb[(size_t)(m0 + tr * 4 + rr) * N + n0 + tc * 4]) = v;
    }
}

// ---------------------------------------------------------------------------
// KV projection GEMM (NT) with bf16 hi/lo split epilogue.
// A = context [b][n][c] (scaled by cscale[n]*gctx[c]); B = Wkv [e2][c].
// Outputs: khi/klo [bh][n][64], vthi/vtlo [bh][64][n] (V transposed), k2[bh][n]
// ---------------------------------------------------------------------------
__global__ __launch_bounds__(256) void k_gemm_kv(const float* __restrict__ Am,
                                                 const float* __restrict__ Bmat,
                                                 const float* __restrict__ rowscale,
                                                 const float* __restrict__ kgamma,
                                                 unsigned short* __restrict__ khi,
                                                 unsigned short* __restrict__ klo,
                                                 unsigned short* __restrict__ vthi,
                                                 unsigned short* __restrict__ vtlo,
                                                 float* __restrict__ k2g) {
    const int b = blockIdx.z;
    const int M = NCTX, K = CDIM;
    const int n0 = blockIdx.x * 64, m0 = blockIdx.y * 64;
    const float* Ab = Am + (size_t)b * M * K;
    __shared__ float As[16][68];
    __shared__ float Bs[16][68];
    const int t = threadIdx.x;
    const int tr = t >> 4, tc = t & 15;
    const int la_k = t & 15, la_m = t >> 4;
    float acc[4][4] = {};

    float rs[4];
#pragma unroll
    for (int i = 0; i < 4; ++i)
        rs[i] = rowscale[(size_t)b * M + m0 + la_m + 16 * i];

    for (int k0 = 0; k0 < K; k0 += 16) {
        __syncthreads();
#pragma unroll
        for (int i = 0; i < 4; ++i) {
            int m = la_m + 16 * i;
            float v = Ab[(size_t)(m0 + m) * K + k0 + la_k];
            v *= rs[i] * kgamma[k0 + la_k];
            As[la_k][m] = v;
        }
#pragma unroll
        for (int i = 0; i < 4; ++i) {
            int n = la_m + 16 * i;
            Bs[la_k][n] = Bmat[(size_t)(n0 + n) * K + k0 + la_k];
        }
        __syncthreads();
#pragma unroll
        for (int kk = 0; kk < 16; ++kk) {
            const float4 a4 = *(const float4*)(&As[kk][tr * 4]);
            const float4 b4 = *(const float4*)(&Bs[kk][tc * 4]);
            const float ar[4] = {a4.x, a4.y, a4.z, a4.w};
            const float bc[4] = {b4.x, b4.y, b4.z, b4.w};
#pragma unroll
            for (int rr = 0; rr < 4; ++rr)
#pragma unroll
                for (int cc = 0; cc < 4; ++cc)
                    acc[rr][cc] = fmaf(ar[rr], bc[cc], acc[rr][cc]);
        }
    }

    // epilogue: split to bf16 hi/lo, frag-ready layouts
    const int hh = (n0 >> 6) & 7;
    const int bh_i = b * 8 + hh;
    if (n0 < EINNER) {
        // K half: [bh][n][d], d = tc*4+cc
#pragma unroll
        for (int rr = 0; rr < 4; ++rr) {
            const int n = m0 + tr * 4 + rr;
            ushort4v h4, l4;
#pragma unroll
            for (int cc = 0; cc < 4; ++cc) {
                unsigned short h = f2bf(acc[rr][cc]);
                h4[cc] = h;
                l4[cc] = f2bf(acc[rr][cc] - bf2f(h));
            }
            *(ushort4v*)(khi + ((size_t)bh_i * NCTX + n) * 64 + tc * 4) = h4;
            *(ushort4v*)(klo + ((size_t)bh_i * NCTX + n) * 64 + tc * 4) = l4;
        }
        // k2 = sum_d k^2 (fp32)
#pragma unroll
        for (int rr = 0; rr < 4; ++rr) {
            float s = 0.f;
#pragma unroll
            for (int cc = 0; cc < 4; ++cc) s = fmaf(acc[rr][cc], acc[rr][cc], s);
            s += __shfl_xor(s, 1, 64);
            s += __shfl_xor(s, 2, 64);
            s += __shfl_xor(s, 4, 64);
            s += __shfl_xor(s, 8, 64);
            if (tc == 0) k2g[(size_t)bh_i * NCTX + m0 + tr * 4 + rr] = s;
        }
    } else {
        // V half: transposed [bh][d][n], d = tc*4+cc
#pragma unroll
        for (int cc = 0; cc < 4; ++cc) {
            const int d = tc * 4 + cc;
            ushort4v h4, l4;
#pragma unroll
            for (int rr = 0; rr < 4; ++rr) {
                unsigned short h = f2bf(acc[rr][cc]);
                h4[rr] = h;
                l4[rr] = f2bf(acc[rr][cc] - bf2f(h));
            }
            *(ushort4v*)(vthi + ((size_t)bh_i * 64 + d) * NCTX + m0 + tr * 4) = h4;
            *(ushort4v*)(vtlo + ((size_t)bh_i * 64 + d) * NCTX + m0 + tr * 4) = l4;
        }
    }
}

// ---------------------------------------------------------------------------
// MFMA flash attention, split-bf16, i/j-split for occupancy.
// Block: 256 thr = 4 waves, 32-query i-tile. Wave w: row-group rg = w>>1
// (16 q-rows), j-half jh = w&1 (512 keys). Each wave runs the R3-verified
// barrier-free online-softmax loop over 8 j-tiles; the two j-half partials
// (unnormalized O, m, l) are combined in LDS at the end.
// Grid 32x64 = 2048 blocks -> 32 waves/CU (was 16): latency-bound fix.
// LDS: per-wave P pool (4608 B) reused as o_un[16][66] f32 at combine time.
// ---------------------------------------------------------------------------
__global__ __launch_bounds__(256) void k_attn_mfma(
    const float* __restrict__ qbuf, const unsigned short* __restrict__ khi,
    const unsigned short* __restrict__ klo, const unsigned short* __restrict__ vthi,
    const unsigned short* __restrict__ vtlo, const float* __restrict__ k2g,
    float* __restrict__ ao) {
    const int bh = blockIdx.y;
    const int i0 = blockIdx.x * 32;
    const int t = threadIdx.x;
    const int w = t >> 6;
    const int rg = w >> 1;        // row-group (16 rows)
    const int jh = w & 1;         // j-half (512 keys)
    const int lane = t & 63;
    const int c = lane & 15, g = lane >> 4;

    // pool: per-wave P staging [16][72] ushort x2 (4608 B) during j-loop;
    // reused as per-wave o_un [16][66] f32 (4224 B) for the combine.
    __shared__ __align__(16) char pool[18432];
    unsigned short* psth = (unsigned short*)(pool + w * 4608);   // [16][72]
    unsigned short* pstl = psth + 16 * 72;
    __shared__ float q2s[32];
    __shared__ float msh[4][16];
    __shared__ float lsh[4][16];

    // ---- Q setup: direct global loads, fp32 ----
    const float* qb = qbuf + (size_t)bh * 64 * XY;
    const int qrow = i0 + 16 * rg + c;
    float qv[16];
#pragma unroll
    for (int kk = 0; kk < 2; ++kk)
#pragma unroll
        for (int i = 0; i < 8; ++i)
            qv[kk * 8 + i] = qb[(size_t)(32 * kk + 8 * g + i) * XY + qrow];

    float s2 = 0.f;
#pragma unroll
    for (int i = 0; i < 16; ++i) s2 = fmaf(qv[i], qv[i], s2);
    s2 += __shfl_xor(s2, 16, 64);
    s2 += __shfl_xor(s2, 32, 64);
    if (g == 0) q2s[16 * rg + c] = s2;   // jh twins write same value: benign
    __syncthreads();
    float q2r[4];
#pragma unroll
    for (int r = 0; r < 4; ++r) q2r[r] = q2s[16 * rg + 4 * g + r];

    bf16x8 qh[2], ql[2];
#pragma unroll
    for (int kk = 0; kk < 2; ++kk)
#pragma unroll
        for (int i = 0; i < 8; ++i) {
            float x = qv[kk * 8 + i];
            unsigned short h = f2bf(x);
            qh[kk][i] = (short)h;
            ql[kk][i] = (short)f2bf(x - bf2f(h));
        }

    const unsigned short* khb = khi + (size_t)bh * NCTX * 64;
    const unsigned short* klb = klo + (size_t)bh * NCTX * 64;
    const unsigned short* vhb = vthi + (size_t)bh * 64 * NCTX;
    const unsigned short* vlb = vtlo + (size_t)bh * 64 * NCTX;
    const float* k2b = k2g + (size_t)bh * NCTX;

    f32x4 acc_o[4] = {{0.f, 0.f, 0.f, 0.f}, {0.f, 0.f, 0.f, 0.f},
                      {0.f, 0.f, 0.f, 0.f}, {0.f, 0.f, 0.f, 0.f}};
    float m_run[4], l_run[4];
#pragma unroll
    for (int r = 0; r < 4; ++r) { m_run[r] = -1e30f; l_run[r] = 0.f; }

    const int jbeg = jh * 512, jend = jbeg + 512;
    for (int j0 = jbeg; j0 < jend; j0 += 64) {
        float p[4][4];
        // ---- scores: 4 col-tiles of 16 keys ----
#pragma unroll
        for (int cc = 0; cc < 4; ++cc) {
            const unsigned short* kr_h = khb + (size_t)(j0 + 16 * cc + c) * 64 + 8 * g;
            const unsigned short* kr_l = klb + (size_t)(j0 + 16 * cc + c) * 64 + 8 * g;
            f32x4 acc = {0.f, 0.f, 0.f, 0.f};
#pragma unroll
            for (int kk = 0; kk < 2; ++kk) {
                bf16x8 kh_ = *(const bf16x8*)(kr_h + 32 * kk);
                bf16x8 kl_ = *(const bf16x8*)(kr_l + 32 * kk);
                acc = __builtin_amdgcn_mfma_f32_16x16x32_bf16(qh[kk], kh_, acc, 0, 0, 0);
                acc = __builtin_amdgcn_mfma_f32_16x16x32_bf16(qh[kk], kl_, acc, 0, 0, 0);
                acc = __builtin_amdgcn_mfma_f32_16x16x32_bf16(ql[kk], kh_, acc, 0, 0, 0);
            }
            float k2v = k2b[j0 + 16 * cc + c];
#pragma unroll
            for (int r = 0; r < 4; ++r) {
                float d2 = q2r[r] + k2v - 2.f * acc[r];
                p[cc][r] = -0.125f * sqrtf(fmaxf(d2, 0.f));
            }
        }
        // ---- online softmax (rows = 4g+r, 16 lanes per row) ----
        float alpha[4];
#pragma unroll
        for (int r = 0; r < 4; ++r) {
            float mt = fmaxf(fmaxf(p[0][r], p[1][r]), fmaxf(p[2][r], p[3][r]));
            mt = fmaxf(mt, __shfl_xor(mt, 1, 64));
            mt = fmaxf(mt, __shfl_xor(mt, 2, 64));
            mt = fmaxf(mt, __shfl_xor(mt, 4, 64));
            mt = fmaxf(mt, __shfl_xor(mt, 8, 64));
            float mn = fmaxf(m_run[r], mt);
            alpha[r] = __expf(m_run[r] - mn);
            m_run[r] = mn;
            float sum = 0.f;
#pragma unroll
            for (int cc = 0; cc < 4; ++cc) {
                float e = __expf(p[cc][r] - mn);
                p[cc][r] = e;
                sum += e;
            }
            sum += __shfl_xor(sum, 1, 64);
            sum += __shfl_xor(sum, 2, 64);
            sum += __shfl_xor(sum, 4, 64);
            sum += __shfl_xor(sum, 8, 64);
            l_run[r] = l_run[r] * alpha[r] + sum;
        }
#pragma unroll
        for (int dt = 0; dt < 4; ++dt)
#pragma unroll
            for (int r = 0; r < 4; ++r) acc_o[dt][r] *= alpha[r];

        // ---- stage split P to per-wave LDS (row = 4g+r, col = 16cc+c) ----
#pragma unroll
        for (int cc = 0; cc < 4; ++cc)
#pragma unroll
            for (int r = 0; r < 4; ++r) {
                float x = p[cc][r];
                unsigned short h = f2bf(x);
                psth[(4 * g + r) * 72 + 16 * cc + c] = h;
                pstl[(4 * g + r) * 72 + 16 * cc + c] = f2bf(x - bf2f(h));
            }
        asm volatile("s_waitcnt lgkmcnt(0)" ::: "memory");
        bf16x8 ph[2], pl[2];
#pragma unroll
        for (int kk = 0; kk < 2; ++kk) {
            ph[kk] = *(const bf16x8*)(psth + c * 72 + 32 * kk + 8 * g);
            pl[kk] = *(const bf16x8*)(pstl + c * 72 + 32 * kk + 8 * g);
        }
        // ---- PV: 4 d-tiles ----
#pragma unroll
        for (int dt = 0; dt < 4; ++dt) {
            const unsigned short* vr_h = vhb + (size_t)(16 * dt + c) * NCTX + j0 + 8 * g;
            const unsigned short* vr_l = vlb + (size_t)(16 * dt + c) * NCTX + j0 + 8 * g;
#pragma unroll
            for (int kk = 0; kk < 2; ++kk) {
                bf16x8 vh_ = *(const bf16x8*)(vr_h + 32 * kk);
                bf16x8 vl_ = *(const bf16x8*)(vr_l + 32 * kk);
                acc_o[dt] = __builtin_amdgcn_mfma_f32_16x16x32_bf16(ph[kk], vh_, acc_o[dt], 0, 0, 0);
                acc_o[dt] = __builtin_amdgcn_mfma_f32_16x16x32_bf16(ph[kk], vl_, acc_o[dt], 0, 0, 0);
                acc_o[dt] = __builtin_amdgcn_mfma_f32_16x16x32_bf16(pl[kk], vh_, acc_o[dt], 0, 0, 0);
            }
        }
    }

    // ---- combine the two j-halves in LDS ----
    __syncthreads();   // all waves done with their P pools
    float* pf = (float*)pool;   // per-wave o_un [16][66] f32 at w*1056 floats
#pragma unroll
    for (int dt = 0; dt < 4; ++dt)
#pragma unroll
        for (int r = 0; r < 4; ++r)
            pf[w * 1056 + (4 * g + r) * 66 + 16 * dt + c] = acc_o[dt][r];
    if (c == 0) {
#pragma unroll
        for (int r = 0; r < 4; ++r) {
            msh[w][4 * g + r] = m_run[r];
            lsh[w][4 * g + r] = l_run[r];
        }
    }
    __syncthreads();

    // combine + write: t -> (q = t&31, d = (t>>5)*8 + dd)
    {
        const int q = t & 31, dblk = t >> 5;
        const int qrg = q >> 4, qr = q & 15;
        const int wA = qrg * 2, wB = wA + 1;
        float m1 = msh[wA][qr], m2 = msh[wB][qr];
        float l1 = lsh[wA][qr], l2 = lsh[wB][qr];
        float M = fmaxf(m1, m2);
        float e1 = __expf(m1 - M), e2 = __expf(m2 - M);
        float inv = 1.f / (e1 * l1 + e2 * l2);
        float w1 = e1 * inv, w2 = e2 * inv;
#pragma unroll
        for (int dd = 0; dd < 8; ++dd) {
            int d = dblk * 8 + dd;
            float o1 = pf[wA * 1056 + qr * 66 + d];
            float o2 = pf[wB * 1056 + qr * 66 + d];
            ao[((size_t)bh * 64 + d) * XY + i0 + q] = w1 * o1 + w2 * o2;
        }
    }
}

// ---------------------------------------------------------------------------
extern "C" void kernel_launch(void* const* d_in, const int* in_sizes, int n_in,
                              void* d_out, int out_size, void* d_ws, size_t ws_size,
                              hipStream_t stream) {
    const float* fmap    = (const float*)d_in[0];
    const float* context = (const float*)d_in[1];
    const float* gfm     = (const float*)d_in[2];
    const float* gctx    = (const float*)d_in[3];
    const float* Wq      = (const float*)d_in[4];
    const float* Wkv     = (const float*)d_in[5];
    const float* Wout    = (const float*)d_in[6];
    float* out = (float*)d_out;

    float* ws = (float*)d_ws;
    float* fscale = ws;                               //     8,192 f32
    float* cscale = ws + 8192;                        //     8,192 f32
    float* qbuf   = ws + 16384;                       // 4,194,304 f32 (q; reused as attn-out)
    float* k2g    = ws + 16384 + 4194304;             //    65,536 f32
    unsigned short* khi  = (unsigned short*)(ws + 16384 + 4194304 + 65536);
    unsigned short* klo  = khi + 4194304;             // each 4M ushort = 8 MB
    unsigned short* vthi = klo + 4194304;
    unsigned short* vtlo = vthi + 4194304;
    // total ws usage ~50.7 MB

    k_fmap_scale<<<32, 256, 0, stream>>>(fmap, fscale);
    k_ctx_scale<<<2048, 256, 0, stream>>>(context, cscale);

    // q[b][e][xy] = Wq[e][c] * (fmap[b][c][xy] * fscale[b][xy] * gfm[c])
    k_gemm_nn<true><<<dim3(16, 8, BATCH), 256, 0, stream>>>(
        Wq, fmap, qbuf, fscale, gfm, EINNER, XY, CDIM);

    // KV projection -> bf16 hi/lo frag-ready buffers + k2
    k_gemm_kv<<<dim3(16, 16, BATCH), 256, 0, stream>>>(
        context, Wkv, cscale, gctx, khi, klo, vthi, vtlo, k2g);

    // MFMA attention (i/j-split); output written in-place over qbuf
    k_attn_mfma<<<dim3(32, 64), 256, 0, stream>>>(
        qbuf, khi, klo, vthi, vtlo, k2g, qbuf);

    // out[b][d][xy] = Wout[d][e] * attnout[b][e][xy]
    k_gemm_nn<false><<<dim3(16, 8, BATCH), 256, 0, stream>>>(
        Wout, qbuf, out, nullptr, nullptr, CDIM, XY, EINNER);
}